// Round 2
// baseline (172.476 us; speedup 1.0000x reference)
//
#include <hip/hip_runtime.h>

// MixtureExperts: out[b,p,d] = sum_k sel[b, idx[b,k]] * W[idx[b,k], p, d]
// BS=2048, NE=64, TK=8, P=32, D=512

constexpr int BS  = 2048;
constexpr int NE  = 64;
constexpr int TK  = 8;
constexpr int PD  = 32 * 512;   // 16384 floats per expert / per output row
constexpr int PD4 = PD / 4;     // 4096 float4

typedef float f32x4 __attribute__((ext_vector_type(4)));

__global__ __launch_bounds__(256) void moe_mix_kernel(
    const float* __restrict__ sel,   // [BS, NE]
    const int*   __restrict__ idx,   // [BS, TK]
    const float* __restrict__ W,     // [NE, PD]
    float*       __restrict__ out)   // [BS, PD]
{
    const int b = blockIdx.x;
    const int t = threadIdx.x;

    // Per-row routing metadata: wave-uniform loads, L1 broadcasts them.
    int   e[TK];
    float s[TK];
#pragma unroll
    for (int k = 0; k < TK; ++k) {
        e[k] = idx[b * TK + k];
        s[k] = sel[b * NE + e[k]];
    }

    const f32x4* __restrict__ W4 = reinterpret_cast<const f32x4*>(W);
    f32x4*       __restrict__ O4 = reinterpret_cast<f32x4*>(out) + (size_t)b * PD4;

    // 4096 float4 per row / 256 threads = 16 per thread.
#pragma unroll 2
    for (int j = 0; j < PD4 / 256; ++j) {
        const int f4 = t + j * 256;
        f32x4 acc = (f32x4)(0.f);
#pragma unroll
        for (int k = 0; k < TK; ++k) {
            const f32x4 w = W4[(size_t)e[k] * PD4 + f4];
            acc += s[k] * w;
        }
        // Non-temporal: keep the 128 MiB output stream from evicting the
        // 4 MiB weight working set out of L2.
        __builtin_nontemporal_store(acc, &O4[f4]);
    }
}

extern "C" void kernel_launch(void* const* d_in, const int* in_sizes, int n_in,
                              void* d_out, int out_size, void* d_ws, size_t ws_size,
                              hipStream_t stream) {
    const float* sel = (const float*)d_in[0];
    const int*   idx = (const int*)d_in[1];
    const float* W   = (const float*)d_in[2];
    float*       out = (float*)d_out;

    moe_mix_kernel<<<dim3(BS), dim3(256), 0, stream>>>(sel, idx, W, out);
}

// Round 5
// 157.326 us; speedup vs baseline: 1.0963x; 1.0963x over previous
//
#include <hip/hip_runtime.h>
#include <hip/hip_bf16.h>

// MixtureExperts: out[b,p,d] = sum_k sel[b, idx[b,k]] * W[idx[b,k], p, d]
// BS=2048, NE=64, TK=8, P=32, D=512
//
// Single-kernel design: each block owns (pd-tile of 512 cols = one p-row,
// batch-block of 128 rows). It stages W[all 64 experts, tile] into LDS as
// bf16 (64 KiB -> 2 blocks/CU), then streams its 128 output rows reading
// weights from LDS. Roofline: 128 MiB output writes ~= 20.3 us.

constexpr int BS = 2048, NE = 64, TK = 8;
constexpr int PD     = 32 * 512;       // 16384 floats per expert / out row
constexpr int TILE   = 512;            // cols per block (= one p row)
constexpr int NTILES = PD / TILE;      // 32
constexpr int RPB    = 128;            // batch rows per block
constexpr int NBB    = BS / RPB;       // 16

typedef float          f32x4 __attribute__((ext_vector_type(4)));
typedef unsigned short u16x4 __attribute__((ext_vector_type(4)));
typedef unsigned short u16x8 __attribute__((ext_vector_type(8)));

__global__ __launch_bounds__(256, 2) void moe_mix_lds(
    const float* __restrict__ sel,   // [BS, NE]
    const int*   __restrict__ idx,   // [BS, TK]
    const float* __restrict__ W,     // [NE, PD]
    float*       __restrict__ out)   // [BS, PD]
{
    __shared__ unsigned short w_lds[NE][TILE];   // 64 KiB bf16 weights
    __shared__ int            i_lds[RPB][TK];    // 4 KiB
    __shared__ float          s_lds[RPB][TK];    // 4 KiB

    const int tile = blockIdx.x & (NTILES - 1);
    const int bb   = blockIdx.x / NTILES;
    const int t    = threadIdx.x;

    // --- stage W[:, tile*512 .. ) as bf16 into LDS (8192 float4 / 256 thr) ---
    for (int i = t; i < NE * TILE / 4; i += 256) {
        const int e  = i / (TILE / 4);
        const int d4 = i % (TILE / 4);
        const f32x4 w4 = *reinterpret_cast<const f32x4*>(
            W + (size_t)e * PD + tile * TILE + d4 * 4);
        u16x4 r;
#pragma unroll
        for (int j = 0; j < 4; ++j) {
            __hip_bfloat16 h = __float2bfloat16(w4[j]);   // library RNE
            r[j] = __builtin_bit_cast(unsigned short, h);
        }
        *reinterpret_cast<u16x4*>(&w_lds[e][d4 * 4]) = r;
    }

    // --- stage this block's idx rows (1024 int32) ---
    {
        const int4* src = reinterpret_cast<const int4*>(idx + (size_t)bb * RPB * TK);
        int4*       dst = reinterpret_cast<int4*>(&i_lds[0][0]);
        for (int i = t; i < RPB * TK / 4; i += 256) dst[i] = src[i];
    }
    __syncthreads();

    // --- gather routing scores: thread t handles row t ---
    if (t < RPB) {
        const int rg = bb * RPB + t;
#pragma unroll
        for (int k = 0; k < TK; ++k)
            s_lds[t][k] = sel[(size_t)rg * NE + i_lds[t][k]];
    }
    __syncthreads();

    // --- main loop: wave w handles rows w, w+4, ... (32 rows each) ---
    const int wave = t >> 6;
    const int lane = t & 63;
    const int d0   = lane * 8;       // this lane's 8 contiguous cols

    for (int r = wave; r < RPB; r += 4) {
        const int rg = bb * RPB + r;
        f32x4 a0 = (f32x4)(0.f);
        f32x4 a1 = (f32x4)(0.f);
#pragma unroll
        for (int k = 0; k < TK; ++k) {
            const int   e = i_lds[r][k];   // wave-uniform -> LDS broadcast
            const float s = s_lds[r][k];
            const u16x8 wv = *reinterpret_cast<const u16x8*>(&w_lds[e][d0]);
#pragma unroll
            for (int m = 0; m < 4; ++m) {
                a0[m] += s * __builtin_bit_cast(float, ((unsigned)wv[m])     << 16);
                a1[m] += s * __builtin_bit_cast(float, ((unsigned)wv[m + 4]) << 16);
            }
        }
        float* op = out + (size_t)rg * PD + tile * TILE + d0;
        *reinterpret_cast<f32x4*>(op)     = a0;
        *reinterpret_cast<f32x4*>(op + 4) = a1;
    }
}

extern "C" void kernel_launch(void* const* d_in, const int* in_sizes, int n_in,
                              void* d_out, int out_size, void* d_ws, size_t ws_size,
                              hipStream_t stream) {
    const float* sel = (const float*)d_in[0];
    const int*   idx = (const int*)d_in[1];
    const float* W   = (const float*)d_in[2];
    float*       out = (float*)d_out;

    moe_mix_lds<<<dim3(NTILES * NBB), dim3(256), 0, stream>>>(sel, idx, W, out);
}

// Round 6
// 155.063 us; speedup vs baseline: 1.1123x; 1.0146x over previous
//
#include <hip/hip_runtime.h>
#include <hip/hip_bf16.h>

// MixtureExperts: out[b,p,d] = sum_k sel[b, idx[b,k]] * W[idx[b,k], p, d]
// BS=2048, NE=64, TK=8, P=32, D=512
//
// Block = (256-col pd-tile, 128 batch rows). Stage W[all 64 experts, tile]
// into LDS as bf16 (32 KiB; total 40 KiB -> 4 blocks/CU, 16 waves/CU),
// then stream 128 output rows from LDS with fp32 accumulation and
// non-temporal stores. tile = bid & 63 pins all batch-blocks of a tile to
// one XCD (1024-block grid, stride-64 siblings share XCD since 64%8==0),
// so each XCD L2 caches only its 512 KiB W-slice.
// Roofline: 128 MiB output writes ~= 21 us.

constexpr int BS = 2048, NE = 64, TK = 8;
constexpr int PD     = 32 * 512;       // 16384 floats per expert / out row
constexpr int TILE   = 256;            // cols per block
constexpr int NTILES = PD / TILE;      // 64
constexpr int RPB    = 128;            // batch rows per block
constexpr int NBB    = BS / RPB;       // 16

typedef float          f32x4 __attribute__((ext_vector_type(4)));
typedef unsigned short u16x4 __attribute__((ext_vector_type(4)));

__global__ __launch_bounds__(256, 4) void moe_mix_lds(
    const float* __restrict__ sel,   // [BS, NE]
    const int*   __restrict__ idx,   // [BS, TK]
    const float* __restrict__ W,     // [NE, PD]
    float*       __restrict__ out)   // [BS, PD]
{
    __shared__ unsigned short w_lds[NE][TILE];   // 32 KiB bf16 weights
    __shared__ int            i_lds[RPB][TK];    // 4 KiB
    __shared__ float          s_lds[RPB][TK];    // 4 KiB

    const int tile = blockIdx.x & (NTILES - 1);
    const int bb   = blockIdx.x >> 6;            // blockIdx / NTILES
    const int t    = threadIdx.x;

    // --- stage W[:, tile*256 ..) as bf16 into LDS (4096 float4 / 256 thr) ---
    for (int i = t; i < NE * TILE / 4; i += 256) {
        const int e  = i / (TILE / 4);
        const int d4 = i % (TILE / 4);
        const f32x4 w4 = *reinterpret_cast<const f32x4*>(
            W + (size_t)e * PD + tile * TILE + d4 * 4);
        u16x4 r;
#pragma unroll
        for (int j = 0; j < 4; ++j) {
            __hip_bfloat16 h = __float2bfloat16(w4[j]);   // library RNE
            r[j] = __builtin_bit_cast(unsigned short, h);
        }
        *reinterpret_cast<u16x4*>(&w_lds[e][d4 * 4]) = r;
    }

    // --- stage this block's idx rows (1024 int32 = 256 int4) ---
    {
        const int4* src = reinterpret_cast<const int4*>(idx + (size_t)bb * RPB * TK);
        int4*       dst = reinterpret_cast<int4*>(&i_lds[0][0]);
        dst[t] = src[t];
    }
    __syncthreads();

    // --- gather routing scores, all 256 threads (4 (row,k) pairs each) ---
    for (int i = t; i < RPB * TK; i += 256) {
        const int r = i >> 3, k = i & 7;
        s_lds[r][k] = sel[(size_t)(bb * RPB + r) * NE + i_lds[r][k]];
    }
    __syncthreads();

    // --- main loop: wave w handles rows w, w+4, ... (32 rows each) ---
    const int wave = t >> 6;
    const int lane = t & 63;
    const int d0   = lane * 4;       // this lane's 4 contiguous cols

    for (int r = wave; r < RPB; r += 4) {
        const int rg = bb * RPB + r;
        f32x4 acc = (f32x4)(0.f);
#pragma unroll
        for (int k = 0; k < TK; ++k) {
            const int   e = i_lds[r][k];   // wave-uniform -> broadcast
            const float s = s_lds[r][k];
            const u16x4 wv = *reinterpret_cast<const u16x4*>(&w_lds[e][d0]);
#pragma unroll
            for (int m = 0; m < 4; ++m)
                acc[m] += s * __builtin_bit_cast(float, ((unsigned)wv[m]) << 16);
        }
        f32x4* op = reinterpret_cast<f32x4*>(out + (size_t)rg * PD + tile * TILE + d0);
        __builtin_nontemporal_store(acc, op);
    }
}

extern "C" void kernel_launch(void* const* d_in, const int* in_sizes, int n_in,
                              void* d_out, int out_size, void* d_ws, size_t ws_size,
                              hipStream_t stream) {
    const float* sel = (const float*)d_in[0];
    const int*   idx = (const int*)d_in[1];
    const float* W   = (const float*)d_in[2];
    float*       out = (float*)d_out;

    moe_mix_lds<<<dim3(NTILES * NBB), dim3(256), 0, stream>>>(sel, idx, W, out);
}